// Round 1
// baseline (2175.991 us; speedup 1.0000x reference)
//
#include <hip/hip_runtime.h>

#define T_SEQ 512
#define HID   50
#define HP    52      // padded hidden (multiple of 4, keeps float4 rows 16B-aligned)
#define BBLK  4       // batch rows per block
#define BLK   256

__global__ __launch_bounds__(BLK, 2)
void lstm2_fused(const float* __restrict__ x,
                 const float* __restrict__ Wih0,
                 const float* __restrict__ Whh0,
                 const float* __restrict__ bih0,
                 const float* __restrict__ bhh0,
                 const float* __restrict__ Wih1,
                 const float* __restrict__ Whh1,
                 const float* __restrict__ bih1,
                 const float* __restrict__ bhh1,
                 const float* __restrict__ Wfc,
                 const float* __restrict__ bfc,
                 float* __restrict__ out)
{
    __shared__ __align__(16) float hA[BBLK][HP];      // layer0 hidden
    __shared__ __align__(16) float hB[BBLK][HP];      // layer1 hidden
    __shared__ __align__(16) float gs[4][BBLK][HP];   // activated gates

    const int tid  = threadIdx.x;
    const int gt   = tid >> 6;        // wave id = gate type (i,f,g,o) in matvec phases
    const int lane = tid & 63;
    const int bb0  = blockIdx.x * BBLK;
    const bool on  = (lane < HID);
    const int  n   = on ? lane : (HID - 1);   // clamp idle lanes to a valid row
    const int  j   = gt * HID + n;            // gate output index in [0,200)

    // zero h buffers (pads stay zero forever; matched by zero weight pads)
    for (int i = tid; i < BBLK * HP; i += BLK) {
        (&hA[0][0])[i] = 0.0f;
        (&hB[0][0])[i] = 0.0f;
    }
    __syncthreads();

    // ---- time-invariant weights into registers (once) ----
    float w0[HP], w1a[HP], w1b[HP];
    #pragma unroll
    for (int k = 0; k < HP; ++k) { w0[k] = 0.f; w1a[k] = 0.f; w1b[k] = 0.f; }
    #pragma unroll
    for (int k = 0; k < HID; ++k) {
        w0 [k] = Whh0[j * HID + k];
        w1a[k] = Wih1[j * HID + k];
        w1b[k] = Whh1[j * HID + k];
    }
    const float wx  = Wih0[j];                // D == 1
    const float b0j = bih0[j] + bhh0[j];
    const float b1j = bih1[j] + bhh1[j];

    // branchless activation: y = sMul * sigmoid(-sIn * p ... ) + sAdd
    // sigmoid: 1/(1+exp(-p));  tanh: 2/(1+exp(-2p)) - 1   (gate 2 = tanh)
    const bool  tnh  = (gt == 2);
    const float sIn  = tnh ? -2.f : -1.f;
    const float sMul = tnh ?  2.f :  1.f;
    const float sAdd = tnh ? -1.f :  0.f;

    float cA = 0.f, cB = 0.f;   // cell states, owned by (wave=batch, lane=unit)

    const float* xrow = x + (long)bb0 * T_SEQ;

    for (int t = 0; t < T_SEQ; ++t) {
        // ================= layer 0: gates = b + Wih0*x_t + Whh0 @ hA =================
        float acc[BBLK];
        #pragma unroll
        for (int b = 0; b < BBLK; ++b)
            acc[b] = fmaf(wx, xrow[b * T_SEQ + t], b0j);

        #pragma unroll
        for (int k4 = 0; k4 < HP / 4; ++k4) {
            float4 hv[BBLK];
            #pragma unroll
            for (int b = 0; b < BBLK; ++b)
                hv[b] = *(const float4*)&hA[b][4 * k4];
            #pragma unroll
            for (int b = 0; b < BBLK; ++b) {
                acc[b] = fmaf(w0[4*k4+0], hv[b].x, acc[b]);
                acc[b] = fmaf(w0[4*k4+1], hv[b].y, acc[b]);
                acc[b] = fmaf(w0[4*k4+2], hv[b].z, acc[b]);
                acc[b] = fmaf(w0[4*k4+3], hv[b].w, acc[b]);
            }
        }

        #pragma unroll
        for (int b = 0; b < BBLK; ++b) {
            float s = 1.f / (1.f + __expf(sIn * acc[b]));
            if (on) gs[gt][b][lane] = fmaf(sMul, s, sAdd);
        }
        __syncthreads();

        // layer0 state update: wave -> batch row, lane -> hidden unit
        if (on) {
            float gi = gs[0][gt][lane];
            float gf = gs[1][gt][lane];
            float gg = gs[2][gt][lane];
            float go = gs[3][gt][lane];
            cA = fmaf(gf, cA, gi * gg);
            float th = 2.f / (1.f + __expf(-2.f * cA)) - 1.f;
            hA[gt][lane] = go * th;
        }
        __syncthreads();

        // ================= layer 1: gates = b + Wih1 @ hA_new + Whh1 @ hB ============
        #pragma unroll
        for (int b = 0; b < BBLK; ++b) acc[b] = b1j;

        #pragma unroll
        for (int k4 = 0; k4 < HP / 4; ++k4) {
            float4 hv[BBLK];
            #pragma unroll
            for (int b = 0; b < BBLK; ++b)
                hv[b] = *(const float4*)&hA[b][4 * k4];
            #pragma unroll
            for (int b = 0; b < BBLK; ++b) {
                acc[b] = fmaf(w1a[4*k4+0], hv[b].x, acc[b]);
                acc[b] = fmaf(w1a[4*k4+1], hv[b].y, acc[b]);
                acc[b] = fmaf(w1a[4*k4+2], hv[b].z, acc[b]);
                acc[b] = fmaf(w1a[4*k4+3], hv[b].w, acc[b]);
            }
        }
        #pragma unroll
        for (int k4 = 0; k4 < HP / 4; ++k4) {
            float4 hv[BBLK];
            #pragma unroll
            for (int b = 0; b < BBLK; ++b)
                hv[b] = *(const float4*)&hB[b][4 * k4];
            #pragma unroll
            for (int b = 0; b < BBLK; ++b) {
                acc[b] = fmaf(w1b[4*k4+0], hv[b].x, acc[b]);
                acc[b] = fmaf(w1b[4*k4+1], hv[b].y, acc[b]);
                acc[b] = fmaf(w1b[4*k4+2], hv[b].z, acc[b]);
                acc[b] = fmaf(w1b[4*k4+3], hv[b].w, acc[b]);
            }
        }

        #pragma unroll
        for (int b = 0; b < BBLK; ++b) {
            float s = 1.f / (1.f + __expf(sIn * acc[b]));
            if (on) gs[gt][b][lane] = fmaf(sMul, s, sAdd);
        }
        __syncthreads();

        // layer1 state update
        if (on) {
            float gi = gs[0][gt][lane];
            float gf = gs[1][gt][lane];
            float gg = gs[2][gt][lane];
            float go = gs[3][gt][lane];
            cB = fmaf(gf, cB, gi * gg);
            float th = 2.f / (1.f + __expf(-2.f * cB)) - 1.f;
            hB[gt][lane] = go * th;
        }
        __syncthreads();
    }

    // ================= classifier: out[b][c] = hB[b] . Wfc[c] + bfc[c] ===============
    if (tid < BBLK * 2) {
        const int b = tid >> 1;
        const int c = tid & 1;
        float a = bfc[c];
        #pragma unroll
        for (int k = 0; k < HID; ++k)
            a = fmaf(Wfc[c * HID + k], hB[b][k], a);
        out[(bb0 + b) * 2 + c] = a;
    }
}

extern "C" void kernel_launch(void* const* d_in, const int* in_sizes, int n_in,
                              void* d_out, int out_size, void* d_ws, size_t ws_size,
                              hipStream_t stream) {
    const float* x    = (const float*)d_in[0];
    const float* Wih0 = (const float*)d_in[1];
    const float* Whh0 = (const float*)d_in[2];
    const float* bih0 = (const float*)d_in[3];
    const float* bhh0 = (const float*)d_in[4];
    const float* Wih1 = (const float*)d_in[5];
    const float* Whh1 = (const float*)d_in[6];
    const float* bih1 = (const float*)d_in[7];
    const float* bhh1 = (const float*)d_in[8];
    const float* Wfc  = (const float*)d_in[9];
    const float* bfc  = (const float*)d_in[10];
    float* out = (float*)d_out;

    const int B = in_sizes[0] / T_SEQ;     // D == 1
    const int grid = B / BBLK;             // 2048/4 = 512 blocks

    hipLaunchKernelGGL(lstm2_fused, dim3(grid), dim3(BLK), 0, stream,
                       x, Wih0, Whh0, bih0, bhh0, Wih1, Whh1, bih1, bhh1,
                       Wfc, bfc, out);
}